// Round 16
// baseline (823.073 us; speedup 1.0000x reference)
//
#include <hip/hip_runtime.h>

constexpr int LDIM  = 128;
constexpr int NNODE = 20000;
constexpr int EM_N  = 100000;
constexpr int EW_N  = 25000;
constexpr int NSTEP = 6;

typedef _Float16 f16;
typedef _Float16 f16x8 __attribute__((ext_vector_type(8)));
typedef _Float16 f16x4 __attribute__((ext_vector_type(4)));
typedef float    f32x4 __attribute__((ext_vector_type(4)));

struct MlpParams {
  const f16*   xb;      // fp16 node features (gather source)
  const f16*   attrInH; // edge: fp16 sorted attr (residual in)
  f16*         attrOutH;
  const float* xIn;     // node: f32 x residual in
  float*       xOut;    // node: f32 x residual out
  f16*         xbOut;   // node: fp16 copy of new x
  const int*   src;
  const int*   dst;
  const int*   oidx;    // edge, last step: sorted pos -> original edge id
  float*       origOut; // edge, last step: d_out region (original order, f32)
  const f16*   gsrc1;   // node: mesh edge attr (sorted, contiguous)
  const f16*   gsrc2;
  const int*   off1;    // node: CSR offsets [NNODE+1]
  const int*   off2;
  const f16*   W1H;     // fp16 [128 n][384 k]
  const f16*   W2H;     // fp16 [128 n][128 k]
  const float* b1;
  const float* b2;
  const float* gam;
  const float* bet;
  int nRows;
};

__device__ __forceinline__ f16x4 cvt4h(f32x4 a, float sc) {
  f16x4 o;
  o[0] = (f16)(a[0] * sc); o[1] = (f16)(a[1] * sc);
  o[2] = (f16)(a[2] * sc); o[3] = (f16)(a[3] * sc);
  return o;
}

// ================= EDGE kernel: fp16 data plane, f32 LN/residual math =======
__launch_bounds__(256, 2)
__global__ void edge_kernel(MlpParams pmA, MlpParams pmB, int blocksA) {
  const bool isA = (int)blockIdx.x < blocksA;
  const MlpParams P = isA ? pmA : pmB;
  const int bid  = isA ? (int)blockIdx.x : (int)blockIdx.x - blocksA;
  const int row0 = bid * 128;

  __shared__ __align__(16) f16 Abuf[128][40];   // stride 80B: aligned, 2-way banks
  __shared__ __align__(16) f16 Bhi[128][40];
  __shared__ __align__(16) f16 Hbuf[128][136];
  __shared__ float b1s[128], b2s[128], gs[128], bes[128];
  __shared__ int   idxa[128], idxb[128];
  __shared__ float sumL[2][128], sqL[2][128];
  __shared__ float muL[128], rsL[128];

  const int t = threadIdx.x;

  if (t < 128) {
    b1s[t] = P.b1[t];
    gs[t]  = P.gam[t];
    int r = row0 + t;
    idxa[t] = (r < P.nRows) ? P.src[r] : 0;
  } else {
    int t2 = t - 128;
    b2s[t2] = P.b2[t2];
    bes[t2] = P.bet[t2];
    int r = row0 + t2;
    idxb[t2] = (r < P.nRows) ? P.dst[r] : 0;
  }
  __syncthreads();

  const int l   = t & 63;
  const int wid = t >> 6;
  const int wr  = wid >> 1, wcc = wid & 1;
  const int lr  = l & 15,  lg  = l >> 4;

  const int  srow  = t >> 1, sh = t & 1;
  const int  sgRow = row0 + srow;
  const bool sval  = sgRow < P.nRows;
  const int  sgC   = sval ? sgRow : 0;

  const f16* bx0 = P.xb + (size_t)idxa[srow] * LDIM + sh * 16;
  const f16* bx1 = P.xb + (size_t)idxb[srow] * LDIM + sh * 16;
  const f16* bx2 = P.attrInH + (size_t)sgC * LDIM + sh * 16;

  const int wrow = t >> 1, wsh = t & 1;
  const f16* w1base = P.W1H + (size_t)wrow * 384 + wsh * 16;

  f32x4 acc[4][4];
#pragma unroll
  for (int i = 0; i < 4; ++i)
#pragma unroll
    for (int j = 0; j < 4; ++j) acc[i][j] = f32x4{0.f, 0.f, 0.f, 0.f};

  const f16x8 z8 = {0, 0, 0, 0, 0, 0, 0, 0};
  f16x8 pB0, pB1, pW0, pW1;
  {
    pB0 = *(const f16x8*)bx0;
    pB1 = *(const f16x8*)(bx0 + 8);
    pW0 = *(const f16x8*)w1base;
    pW1 = *(const f16x8*)(w1base + 8);
  }

  // phase 1: H = relu(A @ W1 + b1), K = 384
#pragma unroll
  for (int kc = 0; kc < 12; ++kc) {
    if (kc > 0) __syncthreads();
    {
      *(f16x8*)&Abuf[srow][sh * 16]     = sval ? pB0 : z8;
      *(f16x8*)&Abuf[srow][sh * 16 + 8] = sval ? pB1 : z8;
      *(f16x8*)&Bhi[wrow][wsh * 16]     = pW0;
      *(f16x8*)&Bhi[wrow][wsh * 16 + 8] = pW1;
    }
    __syncthreads();
    if (kc < 11) {
      const int kn = kc + 1, segn = kn >> 2, partn = kn & 3;
      const f16* bp = (segn == 0 ? bx0 : segn == 1 ? bx1 : bx2) + partn * 32;
      pB0 = *(const f16x8*)bp;
      pB1 = *(const f16x8*)(bp + 8);
      pW0 = *(const f16x8*)(w1base + kn * 32);
      pW1 = *(const f16x8*)(w1base + kn * 32 + 8);
    }
    f16x8 av[4], bh[4];
#pragma unroll
    for (int mi = 0; mi < 4; ++mi)
      av[mi] = *(const f16x8*)&Abuf[wr * 64 + mi * 16 + lr][lg * 8];
#pragma unroll
    for (int ni = 0; ni < 4; ++ni)
      bh[ni] = *(const f16x8*)&Bhi[wcc * 64 + ni * 16 + lr][lg * 8];
#pragma unroll
    for (int mi = 0; mi < 4; ++mi)
#pragma unroll
      for (int ni = 0; ni < 4; ++ni)
        acc[mi][ni] = __builtin_amdgcn_mfma_f32_16x16x32_f16(av[mi], bh[ni], acc[mi][ni], 0, 0, 0);
  }

  // H write (acc dies)
#pragma unroll
  for (int rt = 0; rt < 4; ++rt)
#pragma unroll
    for (int ct = 0; ct < 4; ++ct) {
      const int cc = wcc * 64 + ct * 16 + lr;
      const float bb = b1s[cc];
#pragma unroll
      for (int q = 0; q < 4; ++q) {
        const int rr = wr * 64 + rt * 16 + lg * 4 + q;
        Hbuf[rr][cc] = (f16)fmaxf(acc[rt][ct][q] + bb, 0.f);
      }
    }

  // phase 2: OUT = H @ W2 + b2 (single fp16 W2)
  f32x4 acc2[4][4];
#pragma unroll
  for (int i = 0; i < 4; ++i)
#pragma unroll
    for (int j = 0; j < 4; ++j) acc2[i][j] = f32x4{0.f, 0.f, 0.f, 0.f};

  const f16* w2base = P.W2H + (size_t)wrow * 128 + wsh * 16;
  f16x8 q0 = *(const f16x8*)w2base;
  f16x8 q1 = *(const f16x8*)(w2base + 8);

#pragma unroll
  for (int kc = 0; kc < 4; ++kc) {
    __syncthreads();
    {
      *(f16x8*)&Bhi[wrow][wsh * 16]     = q0;
      *(f16x8*)&Bhi[wrow][wsh * 16 + 8] = q1;
    }
    __syncthreads();
    if (kc < 3) {
      q0 = *(const f16x8*)(w2base + (kc + 1) * 32);
      q1 = *(const f16x8*)(w2base + (kc + 1) * 32 + 8);
    }
    f16x8 av2[4], bh2[4];
#pragma unroll
    for (int rt = 0; rt < 4; ++rt)
      av2[rt] = *(const f16x8*)&Hbuf[wr * 64 + rt * 16 + lr][kc * 32 + lg * 8];
#pragma unroll
    for (int ct = 0; ct < 4; ++ct)
      bh2[ct] = *(const f16x8*)&Bhi[wcc * 64 + ct * 16 + lr][lg * 8];
#pragma unroll
    for (int rt = 0; rt < 4; ++rt)
#pragma unroll
      for (int ct = 0; ct < 4; ++ct)
        acc2[rt][ct] = __builtin_amdgcn_mfma_f32_16x16x32_f16(av2[rt], bh2[ct], acc2[rt][ct], 0, 0, 0);
  }

  // epilogue: b2 + LN stats (f32)
  float s1[4][4], s2[4][4];
#pragma unroll
  for (int rt = 0; rt < 4; ++rt)
#pragma unroll
    for (int q = 0; q < 4; ++q) { s1[rt][q] = 0.f; s2[rt][q] = 0.f; }
#pragma unroll
  for (int rt = 0; rt < 4; ++rt)
#pragma unroll
    for (int ct = 0; ct < 4; ++ct) {
      const float bb = b2s[wcc * 64 + ct * 16 + lr];
#pragma unroll
      for (int q = 0; q < 4; ++q) {
        float v = acc2[rt][ct][q] + bb;
        acc2[rt][ct][q] = v;
        s1[rt][q] += v;
        s2[rt][q] += v * v;
      }
    }
#pragma unroll
  for (int m = 1; m < 16; m <<= 1) {
#pragma unroll
    for (int rt = 0; rt < 4; ++rt)
#pragma unroll
      for (int q = 0; q < 4; ++q) {
        s1[rt][q] += __shfl_xor(s1[rt][q], m);
        s2[rt][q] += __shfl_xor(s2[rt][q], m);
      }
  }
  __syncthreads();
  {
    const int rt = lr >> 2, q = lr & 3;
    const int rr = wr * 64 + rt * 16 + lg * 4 + q;
    sumL[wcc][rr] = s1[rt][q];
    sqL[wcc][rr]  = s2[rt][q];
  }
  __syncthreads();
  if (t < 128) {
    const float tot = sumL[0][t] + sumL[1][t];
    const float tsq = sqL[0][t] + sqL[1][t];
    const float mu  = tot * (1.0f / 128.0f);
    const float var = tsq * (1.0f / 128.0f) - mu * mu;
    muL[t] = mu;
    rsL[t] = rsqrtf(var + 1e-5f);
  }
  __syncthreads();

  // normalize + residual (fp16 state; f32 math) + optional f32 original-order out
#pragma unroll
  for (int rt = 0; rt < 4; ++rt) {
#pragma unroll
    for (int q = 0; q < 4; ++q) {
      const int rr = wr * 64 + rt * 16 + lg * 4 + q;
      const int grow = row0 + rr;
      if (grow < P.nRows) {
        const float mu = muL[rr], rs = rsL[rr];
        const f16* rin = P.attrInH + (size_t)grow * LDIM;
        f16* rout = P.attrOutH + (size_t)grow * LDIM;
        float* rout2 = nullptr;
        if (P.origOut) rout2 = P.origOut + (size_t)P.oidx[grow] * LDIM;
#pragma unroll
        for (int ct = 0; ct < 4; ++ct) {
          const int cc = wcc * 64 + ct * 16 + lr;
          const float o = gs[cc] * (acc2[rt][ct][q] - mu) * rs + bes[cc] + (float)rin[cc];
          rout[cc] = (f16)o;
          if (rout2) rout2[cc] = o;
        }
      }
    }
  }
}

// ============ NODE kernel: BR=32, contiguous fp16 gather ====================
__launch_bounds__(256, 3)
__global__ void node_kernel(MlpParams P) {
  constexpr int BR = 32;
  const int row0 = (int)blockIdx.x * BR;

  __shared__ __align__(16) f16 Abuf[BR][40];
  __shared__ __align__(16) f16 Bhi[128][40];
  __shared__ __align__(16) f16 Hbuf[BR][136];
  __shared__ float b1s[128], b2s[128], gs[128], bes[128];
  __shared__ float sumL[4][BR], sqL[4][BR], muL[BR], rsL[BR];

  const int t = threadIdx.x;
  if (t < 128) { b1s[t] = P.b1[t]; gs[t] = P.gam[t]; }
  else         { b2s[t - 128] = P.b2[t - 128]; bes[t - 128] = P.bet[t - 128]; }

  const int l  = t & 63;
  const int w  = t >> 6;
  const int lr = l & 15, lg = l >> 4;

  const int  srow  = t >> 3, sh = t & 7;   // 8 threads/row; 16 cols each
  const int  sgRow = row0 + srow;
  const bool sval  = sgRow < P.nRows;
  const int  sgC   = sval ? sgRow : 0;
  const int  myPart = sh >> 1, myHalf = sh & 1;

  const int wrow = t >> 1, wsh = t & 1;
  const f16* w1base = P.W1H + (size_t)wrow * 384 + wsh * 16;
  const f16* xrow   = P.xb + (size_t)sgC * LDIM + sh * 16;
  const f16x8 z8 = {0, 0, 0, 0, 0, 0, 0, 0};

  f32x4 acc[2][2];
#pragma unroll
  for (int i = 0; i < 2; ++i)
#pragma unroll
    for (int j = 0; j < 2; ++j) acc[i][j] = f32x4{0.f, 0.f, 0.f, 0.f};

  // hoisted MESH gather (contiguous fp16 rows, f32 accumulation)
  f32x4 g[4];
#pragma unroll
  for (int j = 0; j < 4; ++j) g[j] = f32x4{0.f, 0.f, 0.f, 0.f};
  float scm = 1.f;
  {
    int beg = 0, end = 0;
    if (sval) { beg = P.off1[sgRow]; end = P.off1[sgRow + 1]; }
    for (int i = beg; i < end; ++i) {
      const f16* er = P.gsrc1 + (size_t)i * LDIM + sh * 16;
      const f16x8 v0 = *(const f16x8*)er;
      const f16x8 v1 = *(const f16x8*)(er + 8);
#pragma unroll
      for (int e = 0; e < 8; ++e) {
        g[e >> 2][e & 3]       += (float)v0[e];
        g[2 + (e >> 2)][e & 3] += (float)v1[e];
      }
    }
    scm = 1.0f / (float)max(end - beg, 1);
  }

  __syncthreads();

  float scw = 1.f;
#pragma unroll
  for (int kc = 0; kc < 12; ++kc) {
    const int seg = kc >> 2, part = kc & 3;
    if (kc > 0) __syncthreads();
    {
      if (myPart == part) {
        if (seg == 0) {
          const f16x8* xp = (const f16x8*)xrow;
          *(f16x8*)&Abuf[srow][myHalf * 16]     = sval ? xp[0] : z8;
          *(f16x8*)&Abuf[srow][myHalf * 16 + 8] = sval ? xp[1] : z8;
        } else {
          const float sc = (seg == 1) ? scm : scw;
          *(f16x4*)&Abuf[srow][myHalf * 16 + 0]  = cvt4h(g[0], sc);
          *(f16x4*)&Abuf[srow][myHalf * 16 + 4]  = cvt4h(g[1], sc);
          *(f16x4*)&Abuf[srow][myHalf * 16 + 8]  = cvt4h(g[2], sc);
          *(f16x4*)&Abuf[srow][myHalf * 16 + 12] = cvt4h(g[3], sc);
        }
      }
      const f16* wsrc = w1base + kc * 32;
      *(f16x8*)&Bhi[wrow][wsh * 16]     = *(const f16x8*)wsrc;
      *(f16x8*)&Bhi[wrow][wsh * 16 + 8] = *(const f16x8*)(wsrc + 8);
      if (kc == 7) {
        // mesh g consumed (kc 4-7): reuse for WORLD gather
#pragma unroll
        for (int j = 0; j < 4; ++j) g[j] = f32x4{0.f, 0.f, 0.f, 0.f};
        int beg = 0, end = 0;
        if (sval) { beg = P.off2[sgRow]; end = P.off2[sgRow + 1]; }
        for (int i = beg; i < end; ++i) {
          const f16* er = P.gsrc2 + (size_t)i * LDIM + sh * 16;
          const f16x8 v0 = *(const f16x8*)er;
          const f16x8 v1 = *(const f16x8*)(er + 8);
#pragma unroll
          for (int e = 0; e < 8; ++e) {
            g[e >> 2][e & 3]       += (float)v0[e];
            g[2 + (e >> 2)][e & 3] += (float)v1[e];
          }
        }
        scw = 1.0f / (float)max(end - beg, 1);
      }
    }
    __syncthreads();
    f16x8 av[2], bh[2];
#pragma unroll
    for (int mi = 0; mi < 2; ++mi)
      av[mi] = *(const f16x8*)&Abuf[mi * 16 + lr][lg * 8];
#pragma unroll
    for (int ni = 0; ni < 2; ++ni)
      bh[ni] = *(const f16x8*)&Bhi[w * 32 + ni * 16 + lr][lg * 8];
#pragma unroll
    for (int mi = 0; mi < 2; ++mi)
#pragma unroll
      for (int ni = 0; ni < 2; ++ni)
        acc[mi][ni] = __builtin_amdgcn_mfma_f32_16x16x32_f16(av[mi], bh[ni], acc[mi][ni], 0, 0, 0);
  }

  // H write (acc dies)
#pragma unroll
  for (int mi = 0; mi < 2; ++mi)
#pragma unroll
    for (int ni = 0; ni < 2; ++ni) {
      const int cc = w * 32 + ni * 16 + lr;
      const float bb = b1s[cc];
#pragma unroll
      for (int q = 0; q < 4; ++q) {
        const int rr = mi * 16 + lg * 4 + q;
        Hbuf[rr][cc] = (f16)fmaxf(acc[mi][ni][q] + bb, 0.f);
      }
    }

  // phase 2 (single fp16 W2)
  f32x4 acc2[2][2];
#pragma unroll
  for (int i = 0; i < 2; ++i)
#pragma unroll
    for (int j = 0; j < 2; ++j) acc2[i][j] = f32x4{0.f, 0.f, 0.f, 0.f};

  const f16* w2base = P.W2H + (size_t)wrow * 128 + wsh * 16;
  f16x8 q0 = *(const f16x8*)w2base;
  f16x8 q1 = *(const f16x8*)(w2base + 8);

#pragma unroll
  for (int kc = 0; kc < 4; ++kc) {
    __syncthreads();
    {
      *(f16x8*)&Bhi[wrow][wsh * 16]     = q0;
      *(f16x8*)&Bhi[wrow][wsh * 16 + 8] = q1;
    }
    __syncthreads();
    if (kc < 3) {
      q0 = *(const f16x8*)(w2base + (kc + 1) * 32);
      q1 = *(const f16x8*)(w2base + (kc + 1) * 32 + 8);
    }
    f16x8 av2[2], bh2[2];
#pragma unroll
    for (int mi = 0; mi < 2; ++mi)
      av2[mi] = *(const f16x8*)&Hbuf[mi * 16 + lr][kc * 32 + lg * 8];
#pragma unroll
    for (int ni = 0; ni < 2; ++ni)
      bh2[ni] = *(const f16x8*)&Bhi[w * 32 + ni * 16 + lr][lg * 8];
#pragma unroll
    for (int mi = 0; mi < 2; ++mi)
#pragma unroll
      for (int ni = 0; ni < 2; ++ni)
        acc2[mi][ni] = __builtin_amdgcn_mfma_f32_16x16x32_f16(av2[mi], bh2[ni], acc2[mi][ni], 0, 0, 0);
  }

  // epilogue: b2 + LN stats
  float s1[2][4], s2[2][4];
#pragma unroll
  for (int mi = 0; mi < 2; ++mi)
#pragma unroll
    for (int q = 0; q < 4; ++q) { s1[mi][q] = 0.f; s2[mi][q] = 0.f; }
#pragma unroll
  for (int mi = 0; mi < 2; ++mi)
#pragma unroll
    for (int ni = 0; ni < 2; ++ni) {
      const float bb = b2s[w * 32 + ni * 16 + lr];
#pragma unroll
      for (int q = 0; q < 4; ++q) {
        float v = acc2[mi][ni][q] + bb;
        acc2[mi][ni][q] = v;
        s1[mi][q] += v;
        s2[mi][q] += v * v;
      }
    }
#pragma unroll
  for (int m = 1; m < 16; m <<= 1) {
#pragma unroll
    for (int mi = 0; mi < 2; ++mi)
#pragma unroll
      for (int q = 0; q < 4; ++q) {
        s1[mi][q] += __shfl_xor(s1[mi][q], m);
        s2[mi][q] += __shfl_xor(s2[mi][q], m);
      }
  }
  __syncthreads();
  if (lr < 8) {
    const int mi = lr >> 2, q = lr & 3;
    const int rr = mi * 16 + lg * 4 + q;
    sumL[w][rr] = s1[mi][q];
    sqL[w][rr]  = s2[mi][q];
  }
  __syncthreads();
  if (t < BR) {
    float tot = 0.f, tsq = 0.f;
#pragma unroll
    for (int ww = 0; ww < 4; ++ww) { tot += sumL[ww][t]; tsq += sqL[ww][t]; }
    const float mu  = tot * (1.0f / 128.0f);
    const float var = tsq * (1.0f / 128.0f) - mu * mu;
    muL[t] = mu;
    rsL[t] = rsqrtf(var + 1e-5f);
  }
  __syncthreads();

#pragma unroll
  for (int mi = 0; mi < 2; ++mi) {
#pragma unroll
    for (int q = 0; q < 4; ++q) {
      const int rr = mi * 16 + lg * 4 + q;
      const int grow = row0 + rr;
      if (grow < P.nRows) {
        const float mu = muL[rr], rs = rsL[rr];
        const float* rin = P.xIn + (size_t)grow * LDIM;
        float* rout = P.xOut + (size_t)grow * LDIM;
        f16* xbo = P.xbOut + (size_t)grow * LDIM;
#pragma unroll
        for (int ni = 0; ni < 2; ++ni) {
          const int cc = w * 32 + ni * 16 + lr;
          const float o = gs[cc] * (acc2[mi][ni][q] - mu) * rs + bes[cc] + rin[cc];
          rout[cc] = o;
          xbo[cc] = (f16)o;
        }
      }
    }
  }
}

// ---- prep kernels ----
__global__ void prep_weights(const float* w1a, const float* w1b, const float* w1c,
                             const float* w2a, const float* w2b, const float* w2c,
                             f16* w1h, f16* w2h) {
  int i = blockIdx.x * 256 + threadIdx.x;
  constexpr int N1 = 18 * 128 * 384;
  constexpr int N2 = 18 * 128 * 128;
  if (i < N1) {
    int g = i / (128 * 384);
    int rem = i - g * (128 * 384);
    int n = rem / 384, k = rem - n * 384;
    int m = g / 6, s = g - m * 6;
    const float* src = (m == 0) ? w1a : (m == 1) ? w1b : w1c;
    w1h[i] = (f16)src[(size_t)s * (384 * 128) + (size_t)k * 128 + n];
  } else if (i < N1 + N2) {
    int j = i - N1;
    int g = j / (128 * 128);
    int rem = j - g * (128 * 128);
    int n = rem / 128, k = rem - n * 128;
    int m = g / 6, s = g - m * 6;
    const float* src = (m == 0) ? w2a : (m == 1) ? w2b : w2c;
    w2h[j] = (f16)src[(size_t)s * (128 * 128) + (size_t)k * 128 + n];
  }
}

__global__ void prep_xb(const float* x, f16* xb) {
  int i = blockIdx.x * 256 + threadIdx.x;
  if (i < NNODE * LDIM) xb[i] = (f16)x[i];
}

__global__ void prep_deg(const int* mr, const int* wrcv, int* degm, int* degw) {
  int i = blockIdx.x * 256 + threadIdx.x;
  if (i < EM_N) atomicAdd(&degm[mr[i]], 1);
  else if (i < EM_N + EW_N) atomicAdd(&degw[wrcv[i - EM_N]], 1);
}

__global__ void prep_scan(const int* degm, const int* degw, int* moff, int* woff) {
  __shared__ int part[256];
  const int t = threadIdx.x;
  constexpr int NPT = (NNODE + 255) / 256;
#pragma unroll 1
  for (int pass = 0; pass < 2; ++pass) {
    const int* deg = pass == 0 ? degm : degw;
    int* off = pass == 0 ? moff : woff;
    int s = 0;
    for (int i = 0; i < NPT; ++i) {
      int n = t * NPT + i;
      if (n < NNODE) s += deg[n];
    }
    part[t] = s;
    __syncthreads();
    for (int d = 1; d < 256; d <<= 1) {
      int v = (t >= d) ? part[t - d] : 0;
      __syncthreads();
      part[t] += v;
      __syncthreads();
    }
    int base = (t == 0) ? 0 : part[t - 1];
    for (int i = 0; i < NPT; ++i) {
      int n = t * NPT + i;
      if (n < NNODE) { off[n] = base; base += deg[n]; }
    }
    if (t == 255) off[NNODE] = base;
    __syncthreads();
  }
}

__global__ void prep_fill(const int* ms, const int* mr, const int* wsnd, const int* wrcv,
                          const int* moff, const int* woff,
                          int* mcur, int* wcur, int* mcsr, int* wcsr,
                          int* psm, int* pdm, int* psw, int* pdw) {
  int i = blockIdx.x * 256 + threadIdx.x;
  if (i < EM_N) {
    int d = mr[i];
    int pos = moff[d] + atomicAdd(&mcur[d], 1);
    mcsr[pos] = i;
    psm[pos] = ms[i];
    pdm[pos] = d;
  } else if (i < EM_N + EW_N) {
    int j = i - EM_N;
    int d = wrcv[j];
    int pos = woff[d] + atomicAdd(&wcur[d], 1);
    wcsr[pos] = j;
    psw[pos] = wsnd[j];
    pdw[pos] = d;
  }
}

// permute + f32->fp16 convert edge attrs into dst-sorted layout (8 elems/thread)
__global__ void prep_permute(const float* src_m, const float* src_w,
                             const int* mcsr, const int* wcsr,
                             f16* dst_m, f16* dst_w) {
  long i = (long)blockIdx.x * 256 + threadIdx.x;
  const long NM8 = (long)EM_N * 16, NW8 = (long)EW_N * 16;
  if (i < NM8) {
    long pos = i >> 4, c = (i & 15) * 8;
    const float* s = src_m + (size_t)mcsr[pos] * LDIM + c;
    f16x8 o;
#pragma unroll
    for (int e = 0; e < 8; ++e) o[e] = (f16)s[e];
    *(f16x8*)(dst_m + pos * LDIM + c) = o;
  } else if (i < NM8 + NW8) {
    long j = i - NM8;
    long pos = j >> 4, c = (j & 15) * 8;
    const float* s = src_w + (size_t)wcsr[pos] * LDIM + c;
    f16x8 o;
#pragma unroll
    for (int e = 0; e < 8; ++e) o[e] = (f16)s[e];
    *(f16x8*)(dst_w + pos * LDIM + c) = o;
  }
}

extern "C" void kernel_launch(void* const* d_in, const int* in_sizes, int n_in,
                              void* d_out, int out_size, void* d_ws, size_t ws_size,
                              hipStream_t stream) {
  (void)in_sizes; (void)n_in; (void)out_size; (void)ws_size;
  const float* x_in   = (const float*)d_in[0];
  const float* mea_in = (const float*)d_in[1];
  const float* wea_in = (const float*)d_in[2];
  const int*   mei    = (const int*)d_in[3];
  const int*   wei    = (const int*)d_in[4];
  const float* W1s[3] = { (const float*)d_in[5],  (const float*)d_in[11], (const float*)d_in[17] };
  const float* B1s[3] = { (const float*)d_in[6],  (const float*)d_in[12], (const float*)d_in[18] };
  const float* W2s[3] = { (const float*)d_in[7],  (const float*)d_in[13], (const float*)d_in[19] };
  const float* B2s[3] = { (const float*)d_in[8],  (const float*)d_in[14], (const float*)d_in[20] };
  const float* Gs[3]  = { (const float*)d_in[9],  (const float*)d_in[15], (const float*)d_in[21] };
  const float* Be[3]  = { (const float*)d_in[10], (const float*)d_in[16], (const float*)d_in[22] };

  float* xo  = (float*)d_out;
  float* meo = xo  + (size_t)NNODE * LDIM;
  float* weo = meo + (size_t)EM_N * LDIM;

  // ws layout (~42 MB; ws proven >= 84 MB by R14/R15's sorted-path behavior)
  f16* msort = (f16*)d_ws;
  f16* wsort = msort + (size_t)EM_N * LDIM;
  f16* w1h   = wsort + (size_t)EW_N * LDIM;
  f16* w2h   = w1h + (size_t)18 * 128 * 384;
  f16* xb    = w2h + (size_t)18 * 128 * 128;
  int* degm  = (int*)(xb + (size_t)NNODE * LDIM);
  int* degw  = degm + NNODE;
  int* mcur  = degw + NNODE;
  int* wcur  = mcur + NNODE;
  int* moff  = wcur + NNODE;
  int* woff  = moff + (NNODE + 1);
  int* mcsr  = woff + (NNODE + 1);
  int* wcsr  = mcsr + EM_N;
  int* psm   = wcsr + EW_N;
  int* pdm   = psm + EM_N;
  int* psw   = pdm + EM_N;
  int* pdw   = psw + EW_N;

  hipMemsetAsync(degm, 0, (size_t)4 * NNODE * 4, stream);

  {
    int tot = 18 * 128 * 384 + 18 * 128 * 128;
    prep_weights<<<dim3((tot + 255) / 256), 256, 0, stream>>>(
        W1s[0], W1s[1], W1s[2], W2s[0], W2s[1], W2s[2], w1h, w2h);
  }
  prep_xb<<<dim3((NNODE * LDIM + 255) / 256), 256, 0, stream>>>(x_in, xb);
  prep_deg<<<dim3((EM_N + EW_N + 255) / 256), 256, 0, stream>>>(mei + EM_N, wei + EW_N, degm, degw);
  prep_scan<<<dim3(1), 256, 0, stream>>>(degm, degw, moff, woff);
  prep_fill<<<dim3((EM_N + EW_N + 255) / 256), 256, 0, stream>>>(
      mei, mei + EM_N, wei, wei + EW_N, moff, woff, mcur, wcur, mcsr, wcsr,
      psm, pdm, psw, pdw);
  {
    long tot8 = ((long)EM_N + EW_N) * 16;
    prep_permute<<<dim3((unsigned)((tot8 + 255) / 256)), 256, 0, stream>>>(
        mea_in, wea_in, mcsr, wcsr, msort, wsort);
  }

  const int MB = (EM_N + 127) / 128;   // 782
  const int WB = (EW_N + 127) / 128;   // 196
  const int NB = (NNODE + 31) / 32;    // 625

  const float* xc = x_in;

  for (int s = 0; s < NSTEP; ++s) {
    MlpParams pm{}, pw{}, pn{};
    const bool last = (s == NSTEP - 1);

    pm.xb = xb;
    pm.attrInH = msort; pm.attrOutH = msort;
    pm.src = psm; pm.dst = pdm;
    pm.oidx = mcsr; pm.origOut = last ? meo : nullptr;
    pm.W1H = w1h + (size_t)(0 * 6 + s) * 128 * 384;
    pm.W2H = w2h + (size_t)(0 * 6 + s) * 128 * 128;
    pm.b1 = B1s[0] + s * LDIM; pm.b2 = B2s[0] + s * LDIM;
    pm.gam = Gs[0] + s * LDIM; pm.bet = Be[0] + s * LDIM;
    pm.nRows = EM_N;

    pw.xb = xb;
    pw.attrInH = wsort; pw.attrOutH = wsort;
    pw.src = psw; pw.dst = pdw;
    pw.oidx = wcsr; pw.origOut = last ? weo : nullptr;
    pw.W1H = w1h + (size_t)(1 * 6 + s) * 128 * 384;
    pw.W2H = w2h + (size_t)(1 * 6 + s) * 128 * 128;
    pw.b1 = B1s[1] + s * LDIM; pw.b2 = B2s[1] + s * LDIM;
    pw.gam = Gs[1] + s * LDIM; pw.bet = Be[1] + s * LDIM;
    pw.nRows = EW_N;

    edge_kernel<<<dim3(MB + WB), 256, 0, stream>>>(pm, pw, MB);

    pn.xb = xb; pn.xIn = xc; pn.xOut = xo; pn.xbOut = xb;
    pn.gsrc1 = msort; pn.gsrc2 = wsort;
    pn.off1 = moff; pn.off2 = woff;
    pn.W1H = w1h + (size_t)(2 * 6 + s) * 128 * 384;
    pn.W2H = w2h + (size_t)(2 * 6 + s) * 128 * 128;
    pn.b1 = B1s[2] + s * LDIM; pn.b2 = B2s[2] + s * LDIM;
    pn.gam = Gs[2] + s * LDIM; pn.bet = Be[2] + s * LDIM;
    pn.nRows = NNODE;

    node_kernel<<<dim3(NB), 256, 0, stream>>>(pn);

    xc = xo;
  }
}